// Round 4
// baseline (191.963 us; speedup 1.0000x reference)
//
#include <hip/hip_runtime.h>
#include <hip/hip_cooperative_groups.h>
#include <stdint.h>

namespace cg = cooperative_groups;

// Problem constants (fixed by the reference)
#define BATCH 2
#define SEQ 2048
#define DM 512
#define NH 8
#define DH 64
#define MROWS (BATCH * SEQ)   // 4096
#define NCHUNK 64
#define CHUNK (SEQ / NCHUNK)  // 32

typedef __attribute__((ext_vector_type(8))) short bf16x8;
typedef __attribute__((ext_vector_type(4))) float f32x4;

__device__ __forceinline__ unsigned short f2bf(float f) {
    union { float f; uint32_t u; } x; x.f = f;
    uint32_t r = x.u + 0x7fffu + ((x.u >> 16) & 1u);  // RNE
    return (unsigned short)(r >> 16);
}
__device__ __forceinline__ float bf2f(unsigned short s) {
    union { uint32_t u; float f; } x; x.u = ((uint32_t)s) << 16;
    return x.f;
}

// async global->LDS, 16B per lane; LDS dest = wave-uniform base + lane*16
__device__ __forceinline__ void gl_lds16(const void* g, void* l) {
    __builtin_amdgcn_global_load_lds(
        (const __attribute__((address_space(1))) void*)(uintptr_t)g,
        (__attribute__((address_space(3))) void*)(uint32_t)(uintptr_t)l,
        16, 0, 0);
}

// ============================================================================
// FUSED cooperative kernel: 256 blocks x 512 threads (1 block/CU, trivially
// co-resident).  Waves 0-3 and 4-7 run two independent 4-wave pipelines
// (QK|V in phase 1, two gemm tiles in phase 3) with identical barrier counts.
// LDS: QK 3x16KB = 48KB @ S[0], V 3x12KB = 36KB @ S[24576]  (84 KB total).
// ============================================================================
__global__ __launch_bounds__(512, 2) void fused(
    const float4* __restrict__ x, const float4* __restrict__ Wq,
    const float4* __restrict__ Wk, const float4* __restrict__ Wv,
    const float4* __restrict__ Wo,
    unsigned short* __restrict__ xb, unsigned short* __restrict__ wb,
    float* __restrict__ cA, float* __restrict__ cW,
    unsigned short* __restrict__ V, float* __restrict__ csum,
    unsigned short* __restrict__ Zb, float* __restrict__ out)
{
    __shared__ __align__(16) unsigned short S[43008];   // 84 KB
    cg::grid_group grid = cg::this_grid();

    const int t = threadIdx.x, lane = t & 63, wave = t >> 6;
    const int grp = wave >> 2, w4 = wave & 3;
    const int bid = blockIdx.x;
    const int lr2 = lane >> 2;                               // stage row in seg
    const int csrc = ((lane & 3) ^ ((lane >> 3) & 3)) * 8;   // swizzled src chunk
    const int l15 = lane & 15, q = lane >> 4;

    // ---------------- phase 0: fp32 -> bf16 convert (x + all weights) ------
    {
        ushort4* xbq = (ushort4*)xb;
        ushort4* wbq = (ushort4*)wb;
        int tid0 = bid * 512 + t;
#pragma unroll
        for (int it = 0; it < 6; ++it) {                     // 786432 quads
            int i = tid0 + it * 131072;
            float4 v; ushort4* dst; int off;
            if (i < 524288) {
                v = x[i]; dst = xbq; off = i;
            } else {
                int j = i - 524288;
                if (j < 131072) {            // wqk, interleaved per head
                    int head = j >> 14, rp = (j >> 7) & 127, colq = j & 127;
                    v = (rp < 64) ? Wq[head * 8192 + rp * 128 + colq]
                                  : Wk[head * 8192 + (rp - 64) * 128 + colq];
                } else if (j < 196608) {     // wv direct
                    v = Wv[j - 131072];
                } else {                     // wo direct
                    v = Wo[j - 196608];
                }
                dst = wbq; off = j;
            }
            ushort4 o; o.x = f2bf(v.x); o.y = f2bf(v.y); o.z = f2bf(v.z); o.w = f2bf(v.w);
            dst[off] = o;
        }
    }
    grid.sync();

    // ---------------- phase 1: projections (QK-diag grp0 / V grp1) ---------
    // Both paths: 3-buffer pipeline, 2 tiles in flight, 16 barriers each.
    if (grp == 0) {
        // QK-diag: rows = [x_tile(128) | wqk_head(128)], K=512
        constexpr int TEQ = 256 * 32;                    // 8192 elems / buf
        const int head = bid & 7, m0 = (bid >> 3) * 128;
        const unsigned short* Bw = wb + head * 65536;
        const unsigned short* gb[4];
#pragma unroll
        for (int r = 0; r < 4; r++) {
            int g = (r * 4 + w4) * 16 + lr2;
            gb[r] = (g < 128) ? xb + (size_t)(m0 + g) * 512 + csrc
                              : Bw + (size_t)(g - 128) * 512 + csrc;
        }
        int aoff[2], boff[8];
#pragma unroll
        for (int i = 0; i < 2; i++) {
            int R = w4 * 32 + i * 16 + l15;
            aoff[i] = R * 32 + ((q ^ ((R >> 1) & 3)) * 8);
        }
#pragma unroll
        for (int j = 0; j < 8; j++) {
            int R = 128 + j * 16 + l15;
            boff[j] = R * 32 + ((q ^ ((R >> 1) & 3)) * 8);
        }
        f32x4 acc[2][8];
#pragma unroll
        for (int i = 0; i < 2; i++)
#pragma unroll
            for (int j = 0; j < 8; j++) { f32x4 z = {0.f,0.f,0.f,0.f}; acc[i][j] = z; }

        auto stage = [&](int buf, int tt) {
            const int k0 = tt * 32;
#pragma unroll
            for (int r = 0; r < 4; r++)
                gl_lds16(gb[r] + k0, S + buf * TEQ + (r * 4 + w4) * 512);
        };
        auto compute = [&](int buf) {
            const unsigned short* Sb = S + buf * TEQ;
            bf16x8 af[2], bfr[8];
#pragma unroll
            for (int i = 0; i < 2; i++) af[i] = *(const bf16x8*)(Sb + aoff[i]);
#pragma unroll
            for (int j = 0; j < 8; j++) bfr[j] = *(const bf16x8*)(Sb + boff[j]);
            __builtin_amdgcn_s_setprio(1);
#pragma unroll
            for (int i = 0; i < 2; i++)
#pragma unroll
                for (int j = 0; j < 8; j++)
                    acc[i][j] = __builtin_amdgcn_mfma_f32_16x16x32_bf16(af[i], bfr[j], acc[i][j], 0, 0, 0);
            __builtin_amdgcn_s_setprio(0);
        };

        stage(0, 0); stage(1, 1);                        // 8 loads in flight
        for (int tt = 0; tt < 14; ++tt) {
            asm volatile("s_waitcnt vmcnt(4)" ::: "memory");   // tile tt landed
            __builtin_amdgcn_s_barrier();
            compute(tt % 3);
            stage((tt + 2) % 3, tt + 2);
        }
        asm volatile("s_waitcnt vmcnt(4)" ::: "memory");
        __builtin_amdgcn_s_barrier();
        compute(2);                                       // tile 14
        asm volatile("s_waitcnt vmcnt(0)" ::: "memory");
        __builtin_amdgcn_s_barrier();
        compute(0);                                       // tile 15

        // epilogue: d[row] = sum_h q[h]*k[h]
#pragma unroll
        for (int i = 0; i < 2; i++)
#pragma unroll
            for (int r = 0; r < 4; r++) {
                float d = 0.f;
#pragma unroll
                for (int j = 0; j < 4; j++) d += acc[i][j][r] * acc[i][j + 4][r];
                d += __shfl_xor(d, 1); d += __shfl_xor(d, 2);
                d += __shfl_xor(d, 4); d += __shfl_xor(d, 8);
                if (l15 == 0) {
                    int row = m0 + w4 * 32 + i * 16 + (lane >> 4) * 4 + r;
                    int p = row & (SEQ - 1);
                    float dd = d * 0.125f;
                    float M = fmaxf(dd, 0.f);
                    float a = expf(dd - M), e0 = expf(-M);
                    float Z = a + (float)(SEQ - 1 - p) * e0;
                    cA[row * NH + head] = a / Z;
                    cW[row * NH + head] = e0 / Z;
                }
            }
    } else {
        // V projection: rows = [x_tile(128) | wv_head(64)]
        constexpr int TEV = 192 * 32;                    // 6144 elems / buf
        unsigned short* SV = S + 24576;
        const int head = bid & 7, m0 = (bid >> 3) * 128, n0 = head * 64;
        const unsigned short* Bv = wb + 524288 + (size_t)n0 * 512;
        const unsigned short* gb[3];
#pragma unroll
        for (int r = 0; r < 3; r++) {
            int g = (r * 4 + w4) * 16 + lr2;
            gb[r] = (g < 128) ? xb + (size_t)(m0 + g) * 512 + csrc
                              : Bv + (size_t)(g - 128) * 512 + csrc;
        }
        int aoff[2], boff[4];
#pragma unroll
        for (int i = 0; i < 2; i++) {
            int R = w4 * 32 + i * 16 + l15;
            aoff[i] = R * 32 + ((q ^ ((R >> 1) & 3)) * 8);
        }
#pragma unroll
        for (int j = 0; j < 4; j++) {
            int R = 128 + j * 16 + l15;
            boff[j] = R * 32 + ((q ^ ((R >> 1) & 3)) * 8);
        }
        f32x4 acc[2][4];
#pragma unroll
        for (int i = 0; i < 2; i++)
#pragma unroll
            for (int j = 0; j < 4; j++) { f32x4 z = {0.f,0.f,0.f,0.f}; acc[i][j] = z; }

        auto stage = [&](int buf, int tt) {
            const int k0 = tt * 32;
#pragma unroll
            for (int r = 0; r < 3; r++)
                gl_lds16(gb[r] + k0, SV + buf * TEV + (r * 4 + w4) * 512);
        };
        auto compute = [&](int buf) {
            const unsigned short* Sb = SV + buf * TEV;
            bf16x8 af[2], bfr[4];
#pragma unroll
            for (int i = 0; i < 2; i++) af[i] = *(const bf16x8*)(Sb + aoff[i]);
#pragma unroll
            for (int j = 0; j < 4; j++) bfr[j] = *(const bf16x8*)(Sb + boff[j]);
            __builtin_amdgcn_s_setprio(1);
#pragma unroll
            for (int i = 0; i < 2; i++)
#pragma unroll
                for (int j = 0; j < 4; j++)
                    acc[i][j] = __builtin_amdgcn_mfma_f32_16x16x32_bf16(af[i], bfr[j], acc[i][j], 0, 0, 0);
            __builtin_amdgcn_s_setprio(0);
        };

        stage(0, 0); stage(1, 1);                        // 6 loads in flight
        for (int tt = 0; tt < 14; ++tt) {
            asm volatile("s_waitcnt vmcnt(3)" ::: "memory");
            __builtin_amdgcn_s_barrier();
            compute(tt % 3);
            stage((tt + 2) % 3, tt + 2);
        }
        asm volatile("s_waitcnt vmcnt(3)" ::: "memory");
        __builtin_amdgcn_s_barrier();
        compute(2);
        asm volatile("s_waitcnt vmcnt(0)" ::: "memory");
        __builtin_amdgcn_s_barrier();
        compute(0);

        // V write (bf16)
        const int crow = m0 + w4 * 32 + (lane >> 4) * 4;
#pragma unroll
        for (int i = 0; i < 2; i++)
#pragma unroll
            for (int j = 0; j < 4; j++)
#pragma unroll
                for (int r = 0; r < 4; r++)
                    V[(size_t)(crow + i * 16 + r) * DM + n0 + j * 16 + l15] = f2bf(acc[i][j][r]);
        // csum: per-32-row chunk sums
        float s[4];
#pragma unroll
        for (int j = 0; j < 4; j++) {
            s[j] = 0.f;
#pragma unroll
            for (int i = 0; i < 2; i++)
#pragma unroll
                for (int r = 0; r < 4; r++) s[j] += acc[i][j][r];
            s[j] += __shfl_xor(s[j], 16);
            s[j] += __shfl_xor(s[j], 32);
        }
        if (lane < 16) {
            int bi = (m0 >> 11) * NH + head;
            int chunk = ((m0 & (SEQ - 1)) >> 5) + w4;
#pragma unroll
            for (int j = 0; j < 4; j++)
                csum[(bi * NCHUNK + chunk) * 64 + j * 16 + lane] = s[j];
        }
    }
    grid.sync();

    // ---------------- phase 2: zbuild (suffix-scan scaling) -----------------
    if (wave < 4) {
        int ci = bid * 4 + wave;                 // 1024 chunk-tasks
        int h = lane;
        int c = ci & (NCHUNK - 1), bi = ci >> 6;
        int i = bi & 7, b = bi >> 3;
        float r = 0.f;
#pragma unroll 4
        for (int cc = c + 1; cc < NCHUNK; cc++) r += csum[((bi << 6) + cc) * 64 + h];
#pragma unroll 4
        for (int j = CHUNK - 1; j >= 0; j--) {
            int p = c * CHUNK + j;
            size_t row = (size_t)(b * SEQ + p);
            float v = bf2f(V[row * DM + i * DH + h]);
            float a = cA[row * NH + i], w = cW[row * NH + i];
            Zb[row * DM + i * DH + h] = f2bf(fmaf(a, v, w * r));
            r += v;
        }
    }
    grid.sync();

    // ---------------- phase 3: out = Z @ Wo^T (two 64x64 tiles/block) -------
    {
        constexpr int TEG = 128 * 32;            // 4096 elems / buffer
        unsigned short* SG = S + grp * (3 * TEG);
        const unsigned short* A = Zb;
        const unsigned short* B = wb + 786432;   // Wo bf16 [512,512]
        const int T = grp * 256 + bid;           // tile-task in [0,512)
        const int m0 = (T >> 3) * 64, n0 = (T & 7) * 64;
        const int wm2 = (w4 >> 1) * 32, wn2 = (w4 & 1) * 32;

        const unsigned short* gb[2];
#pragma unroll
        for (int r = 0; r < 2; r++) {
            int g = (r * 4 + w4) * 16 + lr2;
            gb[r] = (g < 64) ? A + (size_t)(m0 + g) * 512 + csrc
                             : B + (size_t)(n0 + g - 64) * 512 + csrc;
        }
        int aoff[2], boff[2];
#pragma unroll
        for (int i = 0; i < 2; i++) {
            int R = wm2 + i * 16 + l15;
            aoff[i] = R * 32 + ((q ^ ((R >> 1) & 3)) * 8);
        }
#pragma unroll
        for (int j = 0; j < 2; j++) {
            int R = 64 + wn2 + j * 16 + l15;
            boff[j] = R * 32 + ((q ^ ((R >> 1) & 3)) * 8);
        }

        f32x4 acc[2][2];
#pragma unroll
        for (int i = 0; i < 2; i++)
#pragma unroll
            for (int j = 0; j < 2; j++) { f32x4 z = {0.f,0.f,0.f,0.f}; acc[i][j] = z; }

        auto stage = [&](int buf, int tt) {
            const int k0 = tt * 32;
#pragma unroll
            for (int r = 0; r < 2; r++)
                gl_lds16(gb[r] + k0, SG + buf * TEG + (r * 4 + w4) * 512);
        };
        auto compute = [&](int buf) {
            const unsigned short* Sb = SG + buf * TEG;
            bf16x8 af[2], bfr[2];
#pragma unroll
            for (int i = 0; i < 2; i++) af[i] = *(const bf16x8*)(Sb + aoff[i]);
#pragma unroll
            for (int j = 0; j < 2; j++) bfr[j] = *(const bf16x8*)(Sb + boff[j]);
            __builtin_amdgcn_s_setprio(1);
#pragma unroll
            for (int i = 0; i < 2; i++)
#pragma unroll
                for (int j = 0; j < 2; j++)
                    acc[i][j] = __builtin_amdgcn_mfma_f32_16x16x32_bf16(af[i], bfr[j], acc[i][j], 0, 0, 0);
            __builtin_amdgcn_s_setprio(0);
        };

        stage(0, 0); stage(1, 1);                // 4 loads in flight
        for (int tt = 0; tt < 14; ++tt) {
            asm volatile("s_waitcnt vmcnt(2)" ::: "memory");
            __builtin_amdgcn_s_barrier();
            compute(tt % 3);
            stage((tt + 2) % 3, tt + 2);
        }
        asm volatile("s_waitcnt vmcnt(2)" ::: "memory");
        __builtin_amdgcn_s_barrier();
        compute(2);
        asm volatile("s_waitcnt vmcnt(0)" ::: "memory");
        __builtin_amdgcn_s_barrier();
        compute(0);

        const int crow = m0 + wm2 + (lane >> 4) * 4;
        const int ccol = n0 + wn2 + l15;
#pragma unroll
        for (int i = 0; i < 2; i++)
#pragma unroll
            for (int j = 0; j < 2; j++)
#pragma unroll
                for (int r = 0; r < 4; r++)
                    out[(size_t)(crow + i * 16 + r) * DM + ccol + j * 16] = acc[i][j][r];
    }
}

// ============================================================================
// FALLBACK: the R2 four-kernel path (known-good, ~101 us), used only if the
// cooperative launch is rejected by the runtime / capture.
// ============================================================================
__global__ void cvt_all(const float4* __restrict__ x,
                        const float4* __restrict__ Wq, const float4* __restrict__ Wk,
                        const float4* __restrict__ Wv, const float4* __restrict__ Wo,
                        ushort4* __restrict__ xb, ushort4* __restrict__ wb) {
    int i = blockIdx.x * blockDim.x + threadIdx.x;   // 786432 quads total
    float4 v; ushort4* dst; int off;
    if (i < 524288) {
        v = x[i]; dst = xb; off = i;
    } else {
        int j = i - 524288;
        if (j < 131072) {
            int head = j >> 14, rp = (j >> 7) & 127, colq = j & 127;
            v = (rp < 64) ? Wq[head * 8192 + rp * 128 + colq]
                          : Wk[head * 8192 + (rp - 64) * 128 + colq];
        } else if (j < 196608) {
            v = Wv[j - 131072];
        } else {
            v = Wo[j - 196608];
        }
        dst = wb; off = j;
    }
    ushort4 o; o.x = f2bf(v.x); o.y = f2bf(v.y); o.z = f2bf(v.z); o.w = f2bf(v.w);
    dst[off] = o;
}

__global__ __launch_bounds__(256) void proj(
    const unsigned short* __restrict__ xb, const unsigned short* __restrict__ wb,
    float* __restrict__ cA, float* __restrict__ cW,
    unsigned short* __restrict__ V, float* __restrict__ csum)
{
    __shared__ __align__(16) unsigned short S[4 * 256 * 32];   // 64 KB
    const int t = threadIdx.x, lane = t & 63, wave = t >> 6;
    const int lr2 = lane >> 2;
    const int csrc = ((lane & 3) ^ ((lane >> 3) & 3)) * 8;
    const int l15 = lane & 15, q = lane >> 4;
    const int bid = blockIdx.x;
    const int wm = wave * 32;

    if (bid < 256) {
        constexpr int TE = 256 * 32;
        const int head = bid & 7, m0 = (bid >> 3) * 128;
        const unsigned short* Bw = wb + head * 65536;
        const unsigned short* gb[4];
#pragma unroll
        for (int r = 0; r < 4; r++) {
            int g = (r * 4 + wave) * 16 + lr2;
            gb[r] = (g < 128) ? xb + (size_t)(m0 + g) * 512 + csrc
                              : Bw + (size_t)(g - 128) * 512 + csrc;
        }
        int aoff[2], boff[8];
#pragma unroll
        for (int i = 0; i < 2; i++) {
            int R = wm + i * 16 + l15;
            aoff[i] = R * 32 + ((q ^ ((R >> 1) & 3)) * 8);
        }
#pragma unroll
        for (int j = 0; j < 8; j++) {
            int R = 128 + j * 16 + l15;
            boff[j] = R * 32 + ((q ^ ((R >> 1) & 3)) * 8);
        }
        f32x4 acc[2][8];
#pragma unroll
        for (int i = 0; i < 2; i++)
#pragma unroll
            for (int j = 0; j < 8; j++) { f32x4 z = {0.f,0.f,0.f,0.f}; acc[i][j] = z; }

        auto stage = [&](int buf, int tt) {
            const int k0 = tt * 32;
#pragma unroll
            for (int r = 0; r < 4; r++)
                gl_lds16(gb[r] + k0, S + buf * TE + (r * 4 + wave) * 512);
        };
        auto compute = [&](int buf) {
            const unsigned short* Sb = S + buf * TE;
            bf16x8 af[2], bfr[8];
#pragma unroll
            for (int i = 0; i < 2; i++) af[i] = *(const bf16x8*)(Sb + aoff[i]);
#pragma unroll
            for (int j = 0; j < 8; j++) bfr[j] = *(const bf16x8*)(Sb + boff[j]);
            __builtin_amdgcn_s_setprio(1);
#pragma unroll
            for (int i = 0; i < 2; i++)
#pragma unroll
                for (int j = 0; j < 8; j++)
                    acc[i][j] = __builtin_amdgcn_mfma_f32_16x16x32_bf16(af[i], bfr[j], acc[i][j], 0, 0, 0);
            __builtin_amdgcn_s_setprio(0);
        };

        stage(0, 0); stage(1, 1); stage(2, 2);
        for (int tt = 0; tt < 14; ++tt) {
            asm volatile("s_waitcnt vmcnt(8)" ::: "memory");
            __builtin_amdgcn_s_barrier();
            compute(tt & 3);
            if (tt <= 12) stage((tt + 3) & 3, tt + 3);
        }
        asm volatile("s_waitcnt vmcnt(4)" ::: "memory");
        __builtin_amdgcn_s_barrier();
        compute(2);
        asm volatile("s_waitcnt vmcnt(0)" ::: "memory");
        __builtin_amdgcn_s_barrier();
        compute(3);

#pragma unroll
        for (int i = 0; i < 2; i++)
#pragma unroll
            for (int r = 0; r < 4; r++) {
                float d = 0.f;
#pragma unroll
                for (int j = 0; j < 4; j++) d += acc[i][j][r] * acc[i][j + 4][r];
                d += __shfl_xor(d, 1); d += __shfl_xor(d, 2);
                d += __shfl_xor(d, 4); d += __shfl_xor(d, 8);
                if (l15 == 0) {
                    int row = m0 + wm + i * 16 + (lane >> 4) * 4 + r;
                    int p = row & (SEQ - 1);
                    float dd = d * 0.125f;
                    float M = fmaxf(dd, 0.f);
                    float a = expf(dd - M), e0 = expf(-M);
                    float Z = a + (float)(SEQ - 1 - p) * e0;
                    cA[row * NH + head] = a / Z;
                    cW[row * NH + head] = e0 / Z;
                }
            }
    } else {
        constexpr int TE2 = 192 * 32;
        const int b2 = bid - 256;
        const int head = b2 & 7, m0 = (b2 >> 3) * 128, n0 = head * 64;
        const unsigned short* Bv = wb + 524288 + (size_t)n0 * 512;
        const unsigned short* gb[3];
#pragma unroll
        for (int r = 0; r < 3; r++) {
            int g = (r * 4 + wave) * 16 + lr2;
            gb[r] = (g < 128) ? xb + (size_t)(m0 + g) * 512 + csrc
                              : Bv + (size_t)(g - 128) * 512 + csrc;
        }
        int aoff[2], boff[4];
#pragma unroll
        for (int i = 0; i < 2; i++) {
            int R = wm + i * 16 + l15;
            aoff[i] = R * 32 + ((q ^ ((R >> 1) & 3)) * 8);
        }
#pragma unroll
        for (int j = 0; j < 4; j++) {
            int R = 128 + j * 16 + l15;
            boff[j] = R * 32 + ((q ^ ((R >> 1) & 3)) * 8);
        }
        f32x4 acc[2][4];
#pragma unroll
        for (int i = 0; i < 2; i++)
#pragma unroll
            for (int j = 0; j < 4; j++) { f32x4 z = {0.f,0.f,0.f,0.f}; acc[i][j] = z; }

        auto stage = [&](int buf, int tt) {
            const int k0 = tt * 32;
#pragma unroll
            for (int r = 0; r < 3; r++)
                gl_lds16(gb[r] + k0, S + buf * TE2 + (r * 4 + wave) * 512);
        };
        auto compute = [&](int buf) {
            const unsigned short* Sb = S + buf * TE2;
            bf16x8 af[2], bfr[4];
#pragma unroll
            for (int i = 0; i < 2; i++) af[i] = *(const bf16x8*)(Sb + aoff[i]);
#pragma unroll
            for (int j = 0; j < 4; j++) bfr[j] = *(const bf16x8*)(Sb + boff[j]);
            __builtin_amdgcn_s_setprio(1);
#pragma unroll
            for (int i = 0; i < 2; i++)
#pragma unroll
                for (int j = 0; j < 4; j++)
                    acc[i][j] = __builtin_amdgcn_mfma_f32_16x16x32_bf16(af[i], bfr[j], acc[i][j], 0, 0, 0);
            __builtin_amdgcn_s_setprio(0);
        };

        stage(0, 0); stage(1, 1); stage(2, 2);
        for (int tt = 0; tt < 14; ++tt) {
            asm volatile("s_waitcnt vmcnt(6)" ::: "memory");
            __builtin_amdgcn_s_barrier();
            compute(tt & 3);
            if (tt <= 12) stage((tt + 3) & 3, tt + 3);
        }
        asm volatile("s_waitcnt vmcnt(3)" ::: "memory");
        __builtin_amdgcn_s_barrier();
        compute(2);
        asm volatile("s_waitcnt vmcnt(0)" ::: "memory");
        __builtin_amdgcn_s_barrier();
        compute(3);

        const int crow = m0 + wm + (lane >> 4) * 4;
#pragma unroll
        for (int i = 0; i < 2; i++)
#pragma unroll
            for (int j = 0; j < 4; j++)
#pragma unroll
                for (int r = 0; r < 4; r++)
                    V[(size_t)(crow + i * 16 + r) * DM + n0 + j * 16 + l15] = f2bf(acc[i][j][r]);
        float s[4];
#pragma unroll
        for (int j = 0; j < 4; j++) {
            s[j] = 0.f;
#pragma unroll
            for (int i = 0; i < 2; i++)
#pragma unroll
                for (int r = 0; r < 4; r++) s[j] += acc[i][j][r];
            s[j] += __shfl_xor(s[j], 16);
            s[j] += __shfl_xor(s[j], 32);
        }
        if (lane < 16) {
            int bi = (m0 >> 11) * NH + head;
            int chunk = ((m0 & (SEQ - 1)) >> 5) + wave;
#pragma unroll
            for (int j = 0; j < 4; j++)
                csum[(bi * NCHUNK + chunk) * 64 + j * 16 + lane] = s[j];
        }
    }
}

__global__ __launch_bounds__(256) void zbuild(
    const unsigned short* __restrict__ V, const float* __restrict__ csum,
    const float* __restrict__ cA, const float* __restrict__ cW,
    unsigned short* __restrict__ Zb) {
    int ci = blockIdx.x * 4 + (threadIdx.x >> 6);
    int h = threadIdx.x & 63;
    int c = ci & (NCHUNK - 1), bi = ci >> 6;
    int i = bi & 7, b = bi >> 3;
    float r = 0.f;
#pragma unroll 4
    for (int cc = c + 1; cc < NCHUNK; cc++) r += csum[((bi << 6) + cc) * 64 + h];
#pragma unroll 4
    for (int j = CHUNK - 1; j >= 0; j--) {
        int p = c * CHUNK + j;
        size_t row = (size_t)(b * SEQ + p);
        float v = bf2f(V[row * DM + i * DH + h]);
        float a = cA[row * NH + i], w = cW[row * NH + i];
        Zb[row * DM + i * DH + h] = f2bf(fmaf(a, v, w * r));
        r += v;
    }
}

template<int TM, int TN, int WM, int WN>
__global__ __launch_bounds__(256) void gemm_bt(
    const unsigned short* __restrict__ A, const unsigned short* __restrict__ B,
    float* __restrict__ C, int M, int N, int K)
{
    constexpr int ROWS = TM + TN;
    static_assert(ROWS == 128, "pipeline waits assume 128 staged rows");
    constexpr int MI = WM / 16, NJ = WN / 16;
    constexpr int WAVES_N = TN / WN;
    constexpr int TE = ROWS * 32;
    __shared__ __align__(16) unsigned short S[4 * TE];   // 32 KB
    const int t = threadIdx.x, lane = t & 63, wave = t >> 6;
    const int wm = (wave / WAVES_N) * WM, wn = (wave % WAVES_N) * WN;
    const int m0 = blockIdx.x * TM, n0 = blockIdx.y * TN;
    const int lr2 = lane >> 2;
    const int csrc = ((lane & 3) ^ ((lane >> 3) & 3)) * 8;
    const int l15 = lane & 15, q = lane >> 4;

    const unsigned short* gb[2];
#pragma unroll
    for (int r = 0; r < 2; r++) {
        int g = (r * 4 + wave) * 16 + lr2;
        gb[r] = (g < TM) ? A + (size_t)(m0 + g) * K + csrc
                         : B + (size_t)(n0 + g - TM) * K + csrc;
    }
    int aoff[MI], boff[NJ];
#pragma unroll
    for (int i = 0; i < MI; i++) {
        int R = wm + i * 16 + l15;
        aoff[i] = R * 32 + ((q ^ ((R >> 1) & 3)) * 8);
    }
#pragma unroll
    for (int j = 0; j < NJ; j++) {
        int R = TM + wn + j * 16 + l15;
        boff[j] = R * 32 + ((q ^ ((R >> 1) & 3)) * 8);
    }

    f32x4 acc[MI][NJ];
#pragma unroll
    for (int i = 0; i < MI; i++)
#pragma unroll
        for (int j = 0; j < NJ; j++) { f32x4 z = {0.f,0.f,0.f,0.f}; acc[i][j] = z; }

    auto stage = [&](int buf, int tt) {
        const int k0 = tt * 32;
#pragma unroll
        for (int r = 0; r < 2; r++)
            gl_lds16(gb[r] + k0, S + buf * TE + (r * 4 + wave) * 512);
    };
    auto compute = [&](int buf) {
        const unsigned short* Sb = S + buf * TE;
        bf16x8 af[MI], bfr[NJ];
#pragma unroll
        for (int i = 0; i < MI; i++) af[i] = *(const bf16x8*)(Sb + aoff[i]);
#pragma unroll
        for (int j = 0; j < NJ; j++) bfr[j] = *(const bf16x8*)(Sb + boff[j]);
        __builtin_amdgcn_s_setprio(1);
#pragma unroll
        for (int i = 0; i < MI; i++)
#pragma unroll
            for (int j = 0; j < NJ; j++)
                acc[i][j] = __builtin_amdgcn_mfma_f32_16x16x32_bf16(af[i], bfr[j], acc[i][j], 0, 0, 0);
        __builtin_amdgcn_s_setprio(0);
    };

    const int NT = K / 32;
    stage(0, 0); stage(1, 1); stage(2, 2);
    for (int tt = 0; tt < NT - 2; ++tt) {
        asm volatile("s_waitcnt vmcnt(4)" ::: "memory");
        __builtin_amdgcn_s_barrier();
        compute(tt & 3);
        if (tt + 3 < NT) stage((tt + 3) & 3, tt + 3);
    }
    asm volatile("s_waitcnt vmcnt(2)" ::: "memory");
    __builtin_amdgcn_s_barrier();
    compute((NT - 2) & 3);
    asm volatile("s_waitcnt vmcnt(0)" ::: "memory");
    __builtin_amdgcn_s_barrier();
    compute((NT - 1) & 3);

    const int crow = m0 + wm + (lane >> 4) * 4;
    const int ccol = n0 + wn + (lane & 15);
#pragma unroll
    for (int i = 0; i < MI; i++)
#pragma unroll
        for (int j = 0; j < NJ; j++)
#pragma unroll
            for (int r = 0; r < 4; r++)
                C[(size_t)(crow + i * 16 + r) * N + ccol + j * 16] = acc[i][j][r];
}

extern "C" void kernel_launch(void* const* d_in, const int* in_sizes, int n_in,
                              void* d_out, int out_size, void* d_ws, size_t ws_size,
                              hipStream_t stream) {
    const float4* x4  = (const float4*)d_in[0];
    const float4* Wq4 = (const float4*)d_in[1];
    const float4* Wk4 = (const float4*)d_in[2];
    const float4* Wv4 = (const float4*)d_in[3];
    const float4* Wo4 = (const float4*)d_in[4];
    float* outp = (float*)d_out;    // [2,2048,512] fp32
    char* ws = (char*)d_ws;         // ~15 MB used

    unsigned short* xbp = (unsigned short*)(ws);             // 4 MB   [4096,512] bf16
    unsigned short* wbp = (unsigned short*)(ws + 4194304);   // 2 MB   wqk|wv|wo bf16
    unsigned short* Vp  = (unsigned short*)(ws + 6291456);   // 4 MB   [4096,512] bf16
    float* cAp = (float*)(ws + 10485760);                    // 128 KB [4096,8]
    float* cWp = (float*)(ws + 10616832);                    // 128 KB
    float* csp = (float*)(ws + 10747904);                    // 256 KB [16*64,64]
    unsigned short* Zbp = (unsigned short*)(ws + 11010048);  // 4 MB   [4096,512] bf16

    void* args[13] = { &x4, &Wq4, &Wk4, &Wv4, &Wo4,
                       &xbp, &wbp, &cAp, &cWp, &Vp, &csp, &Zbp, &outp };
    hipError_t e = hipLaunchCooperativeKernel((const void*)fused,
                                              dim3(256, 1, 1), dim3(512, 1, 1),
                                              args, 0, stream);
    if (e != hipSuccess) {
        (void)hipGetLastError();   // clear sticky error, use fallback path
        cvt_all<<<3072, 256, 0, stream>>>(x4, Wq4, Wk4, Wv4, Wo4,
                                          (ushort4*)xbp, (ushort4*)wbp);
        proj<<<512, 256, 0, stream>>>(xbp, wbp, cAp, cWp, Vp, csp);
        zbuild<<<256, 256, 0, stream>>>(Vp, csp, cAp, cWp, Zbp);
        gemm_bt<64, 64, 32, 32><<<dim3(64, 8, 1), 256, 0, stream>>>(
            Zbp, wbp + 786432, outp, MROWS, DM, DM);
    }
}

// Round 5
// 98.212 us; speedup vs baseline: 1.9546x; 1.9546x over previous
//
#include <hip/hip_runtime.h>
#include <stdint.h>

// Problem constants (fixed by the reference)
#define BATCH 2
#define SEQ 2048
#define DM 512
#define NH 8
#define DH 64
#define MROWS (BATCH * SEQ)   // 4096
#define NCHUNK 64
#define CHUNK (SEQ / NCHUNK)  // 32

typedef __attribute__((ext_vector_type(8))) short bf16x8;
typedef __attribute__((ext_vector_type(4))) float f32x4;

__device__ __forceinline__ unsigned short f2bf(float f) {
    union { float f; uint32_t u; } x; x.f = f;
    uint32_t r = x.u + 0x7fffu + ((x.u >> 16) & 1u);  // RNE
    return (unsigned short)(r >> 16);
}
__device__ __forceinline__ float bf2f(unsigned short s) {
    union { uint32_t u; float f; } x; x.u = ((uint32_t)s) << 16;
    return x.f;
}

// async global->LDS, 16B per lane; LDS dest = wave-uniform base + lane*16
__device__ __forceinline__ void gl_lds16(const void* g, void* l) {
    __builtin_amdgcn_global_load_lds(
        (const __attribute__((address_space(1))) void*)(uintptr_t)g,
        (__attribute__((address_space(3))) void*)(uint32_t)(uintptr_t)l,
        16, 0, 0);
}

// ---- fp32 -> bf16 converts: x + weights, one kernel ------------------------
// wb layout (ushort elems): wqk [0,524288): per head 128 rows (Wq_i 64 | Wk_i 64);
//                           wv  [524288,786432): Wv flat [512,512];
//                           wo  [786432,1048576): Wo flat [512,512].
__global__ void cvt_all(const float4* __restrict__ x,
                        const float4* __restrict__ Wq, const float4* __restrict__ Wk,
                        const float4* __restrict__ Wv, const float4* __restrict__ Wo,
                        ushort4* __restrict__ xb, ushort4* __restrict__ wb) {
    int i = blockIdx.x * blockDim.x + threadIdx.x;   // 786432 quads total
    float4 v; ushort4* dst; int off;
    if (i < 524288) {
        v = x[i]; dst = xb; off = i;
    } else {
        int j = i - 524288;
        if (j < 131072) {            // wqk, interleaved per head
            int head = j >> 14, rp = (j >> 7) & 127, colq = j & 127;
            v = (rp < 64) ? Wq[head * 8192 + rp * 128 + colq]
                          : Wk[head * 8192 + (rp - 64) * 128 + colq];
        } else if (j < 196608) {     // wv direct
            v = Wv[j - 131072];
        } else {                     // wo direct
            v = Wo[j - 196608];
        }
        dst = wb; off = j;
    }
    ushort4 o; o.x = f2bf(v.x); o.y = f2bf(v.y); o.z = f2bf(v.z); o.w = f2bf(v.w);
    dst[off] = o;
}

// ---- fused projection kernel ----------------------------------------------
// BK=32, FOUR LDS buffers, 3 tiles in flight, counted vmcnt (T3/T4).
// XCD-aware task remap (T1): all 16 blocks (8 QK + 8 V heads) that share an
// x m-tile land on the same XCD (XCD = bid%8 = m_tile%8), so the 16x-reused
// x tile is an L2 hit instead of 8 separate HBM fetches.
//   head = (bid>>3)&7,  m_tile = (bid>>6)*8 + (bid&7)   (bijective on [0,256))
__global__ __launch_bounds__(256) void proj(
    const unsigned short* __restrict__ xb, const unsigned short* __restrict__ wb,
    float* __restrict__ cA, float* __restrict__ cW,
    unsigned short* __restrict__ V, float* __restrict__ csum)
{
    __shared__ __align__(16) unsigned short S[4 * 256 * 32];   // 64 KB
    const int t = threadIdx.x, lane = t & 63, wave = t >> 6;
    const int lr2 = lane >> 2;                         // stage row in 16-row seg
    const int csrc = ((lane & 3) ^ ((lane >> 3) & 3)) * 8;  // swizzled src chunk
    const int l15 = lane & 15, q = lane >> 4;
    const int bid = blockIdx.x;
    const int wm = wave * 32;

    if (bid < 256) {
        // ---- QK-diag: rows = [x_tile(128) | wqk_head(128)], K=512 ----
        constexpr int TE = 256 * 32;
        const int head = (bid >> 3) & 7;
        const int m0 = (((bid >> 6) << 3) | (bid & 7)) * 128;
        const unsigned short* Bw = wb + head * 65536;   // [128,512] q|k rows
        const unsigned short* gb[4];
#pragma unroll
        for (int r = 0; r < 4; r++) {
            int g = (r * 4 + wave) * 16 + lr2;
            gb[r] = (g < 128) ? xb + (size_t)(m0 + g) * 512 + csrc
                              : Bw + (size_t)(g - 128) * 512 + csrc;
        }
        int aoff[2], boff[8];
#pragma unroll
        for (int i = 0; i < 2; i++) {
            int R = wm + i * 16 + l15;
            aoff[i] = R * 32 + ((q ^ ((R >> 1) & 3)) * 8);
        }
#pragma unroll
        for (int j = 0; j < 8; j++) {
            int R = 128 + j * 16 + l15;
            boff[j] = R * 32 + ((q ^ ((R >> 1) & 3)) * 8);
        }
        f32x4 acc[2][8];
#pragma unroll
        for (int i = 0; i < 2; i++)
#pragma unroll
            for (int j = 0; j < 8; j++) { f32x4 z = {0.f,0.f,0.f,0.f}; acc[i][j] = z; }

        auto stage = [&](int buf, int tt) {
            const int k0 = tt * 32;
#pragma unroll
            for (int r = 0; r < 4; r++)
                gl_lds16(gb[r] + k0, S + buf * TE + (r * 4 + wave) * 512);
        };
        auto compute = [&](int buf) {
            const unsigned short* Sb = S + buf * TE;
            bf16x8 af[2], bfr[8];
#pragma unroll
            for (int i = 0; i < 2; i++) af[i] = *(const bf16x8*)(Sb + aoff[i]);
#pragma unroll
            for (int j = 0; j < 8; j++) bfr[j] = *(const bf16x8*)(Sb + boff[j]);
            __builtin_amdgcn_s_setprio(1);
#pragma unroll
            for (int i = 0; i < 2; i++)
#pragma unroll
                for (int j = 0; j < 8; j++)
                    acc[i][j] = __builtin_amdgcn_mfma_f32_16x16x32_bf16(af[i], bfr[j], acc[i][j], 0, 0, 0);
            __builtin_amdgcn_s_setprio(0);
        };

        stage(0, 0); stage(1, 1); stage(2, 2);           // 12 loads in flight
        for (int tt = 0; tt < 14; ++tt) {
            asm volatile("s_waitcnt vmcnt(8)" ::: "memory");   // tile tt landed
            __builtin_amdgcn_s_barrier();
            compute(tt & 3);
            if (tt <= 12) stage((tt + 3) & 3, tt + 3);
        }
        asm volatile("s_waitcnt vmcnt(4)" ::: "memory");
        __builtin_amdgcn_s_barrier();
        compute(2);                                       // tile 14
        asm volatile("s_waitcnt vmcnt(0)" ::: "memory");
        __builtin_amdgcn_s_barrier();
        compute(3);                                       // tile 15

        // epilogue: d[row] = sum_h q[h]*k[h]
#pragma unroll
        for (int i = 0; i < 2; i++)
#pragma unroll
            for (int r = 0; r < 4; r++) {
                float d = 0.f;
#pragma unroll
                for (int j = 0; j < 4; j++) d += acc[i][j][r] * acc[i][j + 4][r];
                d += __shfl_xor(d, 1); d += __shfl_xor(d, 2);
                d += __shfl_xor(d, 4); d += __shfl_xor(d, 8);
                if (l15 == 0) {
                    int row = m0 + wm + i * 16 + (lane >> 4) * 4 + r;
                    int p = row & (SEQ - 1);
                    float dd = d * 0.125f;
                    float M = fmaxf(dd, 0.f);
                    float a = expf(dd - M), e0 = expf(-M);
                    float Z = a + (float)(SEQ - 1 - p) * e0;
                    cA[row * NH + head] = a / Z;
                    cW[row * NH + head] = e0 / Z;
                }
            }
    } else {
        // ---- V projection: rows = [x_tile(128) | wv_head(64)] ----
        constexpr int TE2 = 192 * 32;
        const int b2 = bid - 256;
        const int head = (b2 >> 3) & 7;
        const int m0 = (((b2 >> 6) << 3) | (b2 & 7)) * 128;
        const int n0 = head * 64;
        const unsigned short* Bv = wb + 524288 + (size_t)n0 * 512;
        const unsigned short* gb[3];
#pragma unroll
        for (int r = 0; r < 3; r++) {
            int g = (r * 4 + wave) * 16 + lr2;
            gb[r] = (g < 128) ? xb + (size_t)(m0 + g) * 512 + csrc
                              : Bv + (size_t)(g - 128) * 512 + csrc;
        }
        int aoff[2], boff[4];
#pragma unroll
        for (int i = 0; i < 2; i++) {
            int R = wm + i * 16 + l15;
            aoff[i] = R * 32 + ((q ^ ((R >> 1) & 3)) * 8);
        }
#pragma unroll
        for (int j = 0; j < 4; j++) {
            int R = 128 + j * 16 + l15;
            boff[j] = R * 32 + ((q ^ ((R >> 1) & 3)) * 8);
        }
        f32x4 acc[2][4];
#pragma unroll
        for (int i = 0; i < 2; i++)
#pragma unroll
            for (int j = 0; j < 4; j++) { f32x4 z = {0.f,0.f,0.f,0.f}; acc[i][j] = z; }

        auto stage = [&](int buf, int tt) {
            const int k0 = tt * 32;
#pragma unroll
            for (int r = 0; r < 3; r++)
                gl_lds16(gb[r] + k0, S + buf * TE2 + (r * 4 + wave) * 512);
        };
        auto compute = [&](int buf) {
            const unsigned short* Sb = S + buf * TE2;
            bf16x8 af[2], bfr[4];
#pragma unroll
            for (int i = 0; i < 2; i++) af[i] = *(const bf16x8*)(Sb + aoff[i]);
#pragma unroll
            for (int j = 0; j < 4; j++) bfr[j] = *(const bf16x8*)(Sb + boff[j]);
            __builtin_amdgcn_s_setprio(1);
#pragma unroll
            for (int i = 0; i < 2; i++)
#pragma unroll
                for (int j = 0; j < 4; j++)
                    acc[i][j] = __builtin_amdgcn_mfma_f32_16x16x32_bf16(af[i], bfr[j], acc[i][j], 0, 0, 0);
            __builtin_amdgcn_s_setprio(0);
        };

        stage(0, 0); stage(1, 1); stage(2, 2);           // 9 loads in flight
        for (int tt = 0; tt < 14; ++tt) {
            asm volatile("s_waitcnt vmcnt(6)" ::: "memory");
            __builtin_amdgcn_s_barrier();
            compute(tt & 3);
            if (tt <= 12) stage((tt + 3) & 3, tt + 3);
        }
        asm volatile("s_waitcnt vmcnt(3)" ::: "memory");
        __builtin_amdgcn_s_barrier();
        compute(2);
        asm volatile("s_waitcnt vmcnt(0)" ::: "memory");
        __builtin_amdgcn_s_barrier();
        compute(3);

        // V write (bf16): row = m0+wm+i*16+(lane>>4)*4+r, col = n0+j*16+l15
        const int crow = m0 + wm + (lane >> 4) * 4;
#pragma unroll
        for (int i = 0; i < 2; i++)
#pragma unroll
            for (int j = 0; j < 4; j++)
#pragma unroll
                for (int r = 0; r < 4; r++)
                    V[(size_t)(crow + i * 16 + r) * DM + n0 + j * 16 + l15] = f2bf(acc[i][j][r]);
        // csum: this wave's 32 rows = chunk (m0&2047)/32 + wave of (batch, head)
        float s[4];
#pragma unroll
        for (int j = 0; j < 4; j++) {
            s[j] = 0.f;
#pragma unroll
            for (int i = 0; i < 2; i++)
#pragma unroll
                for (int r = 0; r < 4; r++) s[j] += acc[i][j][r];
            s[j] += __shfl_xor(s[j], 16);
            s[j] += __shfl_xor(s[j], 32);
        }
        if (lane < 16) {
            int bi = (m0 >> 11) * NH + head;
            int chunk = ((m0 & (SEQ - 1)) >> 5) + wave;
#pragma unroll
            for (int j = 0; j < 4; j++)
                csum[(bi * NCHUNK + chunk) * 64 + j * 16 + lane] = s[j];
        }
    }
}

// z[q] = a*v[q] + w * sum_{p>q} v[p];  V bf16 in, Zb bf16 out [MROWS,512]
// 256 blocks x 256 threads; each sub-wave handles one chunk (serial len 32)
__global__ __launch_bounds__(256) void zbuild(
    const unsigned short* __restrict__ V, const float* __restrict__ csum,
    const float* __restrict__ cA, const float* __restrict__ cW,
    unsigned short* __restrict__ Zb) {
    int ci = blockIdx.x * 4 + (threadIdx.x >> 6);
    int h = threadIdx.x & 63;
    int c = ci & (NCHUNK - 1), bi = ci >> 6;
    int i = bi & 7, b = bi >> 3;
    float r = 0.f;
#pragma unroll 4
    for (int cc = c + 1; cc < NCHUNK; cc++) r += csum[((bi << 6) + cc) * 64 + h];
#pragma unroll 4
    for (int j = CHUNK - 1; j >= 0; j--) {
        int p = c * CHUNK + j;
        size_t row = (size_t)(b * SEQ + p);
        float v = bf2f(V[row * DM + i * DH + h]);
        float a = cA[row * NH + i], w = cW[row * NH + i];
        Zb[row * DM + i * DH + h] = f2bf(fmaf(a, v, w * r));
        r += v;
    }
}

// ---- C[M,N] = A[M,K] * B[N,K]^T (bf16 in, fp32 out), BK=32 4-buf -----------
template<int TM, int TN, int WM, int WN>
__global__ __launch_bounds__(256) void gemm_bt(
    const unsigned short* __restrict__ A, const unsigned short* __restrict__ B,
    float* __restrict__ C, int M, int N, int K)
{
    constexpr int ROWS = TM + TN;            // must be 128 (SPW=2, vmcnt imms)
    static_assert(ROWS == 128, "pipeline waits assume 128 staged rows");
    constexpr int MI = WM / 16, NJ = WN / 16;
    constexpr int WAVES_N = TN / WN;
    constexpr int TE = ROWS * 32;            // 4096 elems / buffer
    __shared__ __align__(16) unsigned short S[4 * TE];   // 32 KB
    const int t = threadIdx.x, lane = t & 63, wave = t >> 6;
    const int wm = (wave / WAVES_N) * WM, wn = (wave % WAVES_N) * WN;
    const int m0 = blockIdx.x * TM, n0 = blockIdx.y * TN;
    const int lr2 = lane >> 2;
    const int csrc = ((lane & 3) ^ ((lane >> 3) & 3)) * 8;
    const int l15 = lane & 15, q = lane >> 4;

    const unsigned short* gb[2];
#pragma unroll
    for (int r = 0; r < 2; r++) {
        int g = (r * 4 + wave) * 16 + lr2;
        gb[r] = (g < TM) ? A + (size_t)(m0 + g) * K + csrc
                         : B + (size_t)(n0 + g - TM) * K + csrc;
    }
    int aoff[MI], boff[NJ];
#pragma unroll
    for (int i = 0; i < MI; i++) {
        int R = wm + i * 16 + l15;
        aoff[i] = R * 32 + ((q ^ ((R >> 1) & 3)) * 8);
    }
#pragma unroll
    for (int j = 0; j < NJ; j++) {
        int R = TM + wn + j * 16 + l15;
        boff[j] = R * 32 + ((q ^ ((R >> 1) & 3)) * 8);
    }

    f32x4 acc[MI][NJ];
#pragma unroll
    for (int i = 0; i < MI; i++)
#pragma unroll
        for (int j = 0; j < NJ; j++) { f32x4 z = {0.f,0.f,0.f,0.f}; acc[i][j] = z; }

    auto stage = [&](int buf, int tt) {
        const int k0 = tt * 32;
#pragma unroll
        for (int r = 0; r < 2; r++)
            gl_lds16(gb[r] + k0, S + buf * TE + (r * 4 + wave) * 512);
    };
    auto compute = [&](int buf) {
        const unsigned short* Sb = S + buf * TE;
        bf16x8 af[MI], bfr[NJ];
#pragma unroll
        for (int i = 0; i < MI; i++) af[i] = *(const bf16x8*)(Sb + aoff[i]);
#pragma unroll
        for (int j = 0; j < NJ; j++) bfr[j] = *(const bf16x8*)(Sb + boff[j]);
        __builtin_amdgcn_s_setprio(1);
#pragma unroll
        for (int i = 0; i < MI; i++)
#pragma unroll
            for (int j = 0; j < NJ; j++)
                acc[i][j] = __builtin_amdgcn_mfma_f32_16x16x32_bf16(af[i], bfr[j], acc[i][j], 0, 0, 0);
        __builtin_amdgcn_s_setprio(0);
    };

    const int NT = K / 32;                   // 16 for K=512
    stage(0, 0); stage(1, 1); stage(2, 2);   // 6 loads in flight
    for (int tt = 0; tt < NT - 2; ++tt) {
        asm volatile("s_waitcnt vmcnt(4)" ::: "memory");
        __builtin_amdgcn_s_barrier();
        compute(tt & 3);
        if (tt + 3 < NT) stage((tt + 3) & 3, tt + 3);
    }
    asm volatile("s_waitcnt vmcnt(2)" ::: "memory");
    __builtin_amdgcn_s_barrier();
    compute((NT - 2) & 3);
    asm volatile("s_waitcnt vmcnt(0)" ::: "memory");
    __builtin_amdgcn_s_barrier();
    compute((NT - 1) & 3);

    const int crow = m0 + wm + (lane >> 4) * 4;
    const int ccol = n0 + wn + (lane & 15);
#pragma unroll
    for (int i = 0; i < MI; i++)
#pragma unroll
        for (int j = 0; j < NJ; j++)
#pragma unroll
            for (int r = 0; r < 4; r++)
                C[(size_t)(crow + i * 16 + r) * N + ccol + j * 16] = acc[i][j][r];
}

extern "C" void kernel_launch(void* const* d_in, const int* in_sizes, int n_in,
                              void* d_out, int out_size, void* d_ws, size_t ws_size,
                              hipStream_t stream) {
    const float* x  = (const float*)d_in[0];
    const float* Wq = (const float*)d_in[1];
    const float* Wk = (const float*)d_in[2];
    const float* Wv = (const float*)d_in[3];
    const float* Wo = (const float*)d_in[4];
    float* out = (float*)d_out;     // [2,2048,512] fp32
    char* ws = (char*)d_ws;         // ~15 MB used

    unsigned short* xb = (unsigned short*)(ws);             // 4 MB   [4096,512] bf16
    unsigned short* wb = (unsigned short*)(ws + 4194304);   // 2 MB   wqk|wv|wo bf16
    unsigned short* V  = (unsigned short*)(ws + 6291456);   // 4 MB   [4096,512] bf16
    float* cA = (float*)(ws + 10485760);                    // 128 KB [4096,8]
    float* cW = (float*)(ws + 10616832);                    // 128 KB
    float* cs = (float*)(ws + 10747904);                    // 256 KB [16*64,64]
    unsigned short* Zb = (unsigned short*)(ws + 11010048);  // 4 MB   [4096,512] bf16

    cvt_all<<<3072, 256, 0, stream>>>((const float4*)x, (const float4*)Wq,
                                      (const float4*)Wk, (const float4*)Wv,
                                      (const float4*)Wo, (ushort4*)xb, (ushort4*)wb);
    proj<<<512, 256, 0, stream>>>(xb, wb, cA, cW, V, cs);
    zbuild<<<256, 256, 0, stream>>>(V, cs, cA, cW, Zb);
    // out = Z @ Wo^T; 64x64 tile -> 512 blocks (2/CU)
    gemm_bt<64, 64, 32, 32><<<dim3(64, 8, 1), 256, 0, stream>>>(
        Zb, wb + 786432, out, MROWS, DM, DM);
}

// Round 6
// 95.641 us; speedup vs baseline: 2.0071x; 1.0269x over previous
//
#include <hip/hip_runtime.h>
#include <stdint.h>

// Problem constants (fixed by the reference)
#define BATCH 2
#define SEQ 2048
#define DM 512
#define NH 8
#define DH 64
#define MROWS (BATCH * SEQ)   // 4096
#define NCHUNK 64
#define CHUNK (SEQ / NCHUNK)  // 32

typedef __attribute__((ext_vector_type(8))) short bf16x8;
typedef __attribute__((ext_vector_type(4))) float f32x4;

__device__ __forceinline__ unsigned short f2bf(float f) {
    union { float f; uint32_t u; } x; x.f = f;
    uint32_t r = x.u + 0x7fffu + ((x.u >> 16) & 1u);  // RNE
    return (unsigned short)(r >> 16);
}
__device__ __forceinline__ float bf2f(unsigned short s) {
    union { uint32_t u; float f; } x; x.u = ((uint32_t)s) << 16;
    return x.f;
}

// async global->LDS, 16B per lane; LDS dest = wave-uniform base + lane*16
__device__ __forceinline__ void gl_lds16(const void* g, void* l) {
    __builtin_amdgcn_global_load_lds(
        (const __attribute__((address_space(1))) void*)(uintptr_t)g,
        (__attribute__((address_space(3))) void*)(uint32_t)(uintptr_t)l,
        16, 0, 0);
}

// pack 2 f32 -> 2 bf16 (RNE), dst.lo = a, dst.hi = b
__device__ __forceinline__ uint32_t cvtpk(float a, float b) {
    uint32_t d;
    asm volatile("v_cvt_pk_bf16_f32 %0, %1, %2" : "=v"(d) : "v"(a), "v"(b));
    return d;
}

// ---- projection kernel with INLINE fp32->bf16 staging ----------------------
// Reads x / Wq / Wk / Wv directly in fp32: per k-step each lane loads its
// (pre-swizzled) 8-elem row chunk as 2x float4, converts via v_cvt_pk_bf16_f32,
// and ds_write_b128's to the EXACT address global_load_lds used before
// (base + lane*16B) -> fragment/compute code identical to R5.
// 2-deep pipeline (T14 split): load(t+2) issued before compute(t); counted
// vmcnt so one tile's loads stay in flight across the barrier.
// XCD-aware task remap (T1) kept from R5: XCD = bid%8 = m_tile%8.
__global__ __launch_bounds__(256, 2) void proj(
    const float* __restrict__ xf, const float* __restrict__ Wqf,
    const float* __restrict__ Wkf, const float* __restrict__ Wvf,
    float* __restrict__ cA, float* __restrict__ cW,
    unsigned short* __restrict__ V, float* __restrict__ csum)
{
    __shared__ __align__(16) unsigned short S[2 * 256 * 32];   // 32 KB
    const int t = threadIdx.x, lane = t & 63, wave = t >> 6;
    const int lr2 = lane >> 2;                         // stage row in 16-row seg
    const int csrc = ((lane & 3) ^ ((lane >> 3) & 3)) * 8;  // swizzled src chunk
    const int l15 = lane & 15, q = lane >> 4;
    const int bid = blockIdx.x;
    const int wm = wave * 32;

    if (bid < 256) {
        // ---- QK-diag: rows = [x_tile(128) | Wq_head(64) | Wk_head(64)] ----
        constexpr int TE = 256 * 32;
        const int head = (bid >> 3) & 7;
        const int m0 = (((bid >> 6) << 3) | (bid & 7)) * 128;
        const float* gf[4];
#pragma unroll
        for (int r = 0; r < 4; r++) {
            int g = (r * 4 + wave) * 16 + lr2;
            gf[r] = (g < 128) ? xf + (size_t)(m0 + g) * 512 + csrc
                  : (g < 192) ? Wqf + (size_t)(head * 64 + g - 128) * 512 + csrc
                              : Wkf + (size_t)(head * 64 + g - 192) * 512 + csrc;
        }
        int aoff[2], boff[8];
#pragma unroll
        for (int i = 0; i < 2; i++) {
            int R = wm + i * 16 + l15;
            aoff[i] = R * 32 + ((q ^ ((R >> 1) & 3)) * 8);
        }
#pragma unroll
        for (int j = 0; j < 8; j++) {
            int R = 128 + j * 16 + l15;
            boff[j] = R * 32 + ((q ^ ((R >> 1) & 3)) * 8);
        }
        f32x4 acc[2][8];
#pragma unroll
        for (int i = 0; i < 2; i++)
#pragma unroll
            for (int j = 0; j < 8; j++) { f32x4 z = {0.f,0.f,0.f,0.f}; acc[i][j] = z; }

        float4 RA[4][2], RB[4][2];
        auto load = [&](float4 (&R)[4][2], int tt) {
            const int k0 = tt * 32;
#pragma unroll
            for (int r = 0; r < 4; r++) {
                R[r][0] = *(const float4*)(gf[r] + k0);
                R[r][1] = *(const float4*)(gf[r] + k0 + 4);
            }
        };
        auto cw = [&](float4 (&R)[4][2], int buf) {
#pragma unroll
            for (int r = 0; r < 4; r++) {
                uint4 o;
                o.x = cvtpk(R[r][0].x, R[r][0].y);
                o.y = cvtpk(R[r][0].z, R[r][0].w);
                o.z = cvtpk(R[r][1].x, R[r][1].y);
                o.w = cvtpk(R[r][1].z, R[r][1].w);
                *(uint4*)(S + buf * TE + (r * 4 + wave) * 512 + lane * 8) = o;
            }
        };
        auto compute = [&](int buf) {
            const unsigned short* Sb = S + buf * TE;
            bf16x8 af[2], bfr[8];
#pragma unroll
            for (int i = 0; i < 2; i++) af[i] = *(const bf16x8*)(Sb + aoff[i]);
#pragma unroll
            for (int j = 0; j < 8; j++) bfr[j] = *(const bf16x8*)(Sb + boff[j]);
            __builtin_amdgcn_s_setprio(1);
#pragma unroll
            for (int i = 0; i < 2; i++)
#pragma unroll
                for (int j = 0; j < 8; j++)
                    acc[i][j] = __builtin_amdgcn_mfma_f32_16x16x32_bf16(af[i], bfr[j], acc[i][j], 0, 0, 0);
            __builtin_amdgcn_s_setprio(0);
        };

        load(RA, 0); load(RB, 1);                        // 16 loads in flight
        asm volatile("s_waitcnt vmcnt(8)" ::: "memory"); // RA (tile 0) arrived
        cw(RA, 0);
        asm volatile("s_waitcnt lgkmcnt(0)" ::: "memory");
        __builtin_amdgcn_s_barrier();
        for (int tt = 0; tt < 14; tt += 2) {
            load(RA, tt + 2);
            compute(0);                                  // tile tt
            asm volatile("s_waitcnt vmcnt(8)" ::: "memory");  // RB arrived
            cw(RB, 1);                                   // tile tt+1
            asm volatile("s_waitcnt lgkmcnt(0)" ::: "memory");
            __builtin_amdgcn_s_barrier();
            load(RB, tt + 3);
            compute(1);                                  // tile tt+1
            asm volatile("s_waitcnt vmcnt(8)" ::: "memory");  // RA arrived
            cw(RA, 0);                                   // tile tt+2
            asm volatile("s_waitcnt lgkmcnt(0)" ::: "memory");
            __builtin_amdgcn_s_barrier();
        }
        compute(0);                                      // tile 14
        asm volatile("s_waitcnt vmcnt(0)" ::: "memory");
        cw(RB, 1);                                       // tile 15
        asm volatile("s_waitcnt lgkmcnt(0)" ::: "memory");
        __builtin_amdgcn_s_barrier();
        compute(1);                                      // tile 15

        // epilogue: d[row] = sum_h q[h]*k[h]
#pragma unroll
        for (int i = 0; i < 2; i++)
#pragma unroll
            for (int r = 0; r < 4; r++) {
                float d = 0.f;
#pragma unroll
                for (int j = 0; j < 4; j++) d += acc[i][j][r] * acc[i][j + 4][r];
                d += __shfl_xor(d, 1); d += __shfl_xor(d, 2);
                d += __shfl_xor(d, 4); d += __shfl_xor(d, 8);
                if (l15 == 0) {
                    int row = m0 + wm + i * 16 + (lane >> 4) * 4 + r;
                    int p = row & (SEQ - 1);
                    float dd = d * 0.125f;
                    float M = fmaxf(dd, 0.f);
                    float a = expf(dd - M), e0 = expf(-M);
                    float Z = a + (float)(SEQ - 1 - p) * e0;
                    cA[row * NH + head] = a / Z;
                    cW[row * NH + head] = e0 / Z;
                }
            }
    } else {
        // ---- V projection: rows = [x_tile(128) | Wv_head(64)] ----
        constexpr int TE2 = 192 * 32;
        const int b2 = bid - 256;
        const int head = (b2 >> 3) & 7;
        const int m0 = (((b2 >> 6) << 3) | (b2 & 7)) * 128;
        const int n0 = head * 64;
        const float* gf[3];
#pragma unroll
        for (int r = 0; r < 3; r++) {
            int g = (r * 4 + wave) * 16 + lr2;
            gf[r] = (g < 128) ? xf + (size_t)(m0 + g) * 512 + csrc
                              : Wvf + (size_t)(head * 64 + g - 128) * 512 + csrc;
        }
        int aoff[2], boff[4];
#pragma unroll
        for (int i = 0; i < 2; i++) {
            int R = wm + i * 16 + l15;
            aoff[i] = R * 32 + ((q ^ ((R >> 1) & 3)) * 8);
        }
#pragma unroll
        for (int j = 0; j < 4; j++) {
            int R = 128 + j * 16 + l15;
            boff[j] = R * 32 + ((q ^ ((R >> 1) & 3)) * 8);
        }
        f32x4 acc[2][4];
#pragma unroll
        for (int i = 0; i < 2; i++)
#pragma unroll
            for (int j = 0; j < 4; j++) { f32x4 z = {0.f,0.f,0.f,0.f}; acc[i][j] = z; }

        float4 RA[3][2], RB[3][2];
        auto load = [&](float4 (&R)[3][2], int tt) {
            const int k0 = tt * 32;
#pragma unroll
            for (int r = 0; r < 3; r++) {
                R[r][0] = *(const float4*)(gf[r] + k0);
                R[r][1] = *(const float4*)(gf[r] + k0 + 4);
            }
        };
        auto cw = [&](float4 (&R)[3][2], int buf) {
#pragma unroll
            for (int r = 0; r < 3; r++) {
                uint4 o;
                o.x = cvtpk(R[r][0].x, R[r][0].y);
                o.y = cvtpk(R[r][0].z, R[r][0].w);
                o.z = cvtpk(R[r][1].x, R[r][1].y);
                o.w = cvtpk(R[r][1].z, R[r][1].w);
                *(uint4*)(S + buf * TE2 + (r * 4 + wave) * 512 + lane * 8) = o;
            }
        };
        auto compute = [&](int buf) {
            const unsigned short* Sb = S + buf * TE2;
            bf16x8 af[2], bfr[4];
#pragma unroll
            for (int i = 0; i < 2; i++) af[i] = *(const bf16x8*)(Sb + aoff[i]);
#pragma unroll
            for (int j = 0; j < 4; j++) bfr[j] = *(const bf16x8*)(Sb + boff[j]);
            __builtin_amdgcn_s_setprio(1);
#pragma unroll
            for (int i = 0; i < 2; i++)
#pragma unroll
                for (int j = 0; j < 4; j++)
                    acc[i][j] = __builtin_amdgcn_mfma_f32_16x16x32_bf16(af[i], bfr[j], acc[i][j], 0, 0, 0);
            __builtin_amdgcn_s_setprio(0);
        };

        load(RA, 0); load(RB, 1);                        // 12 loads in flight
        asm volatile("s_waitcnt vmcnt(6)" ::: "memory");
        cw(RA, 0);
        asm volatile("s_waitcnt lgkmcnt(0)" ::: "memory");
        __builtin_amdgcn_s_barrier();
        for (int tt = 0; tt < 14; tt += 2) {
            load(RA, tt + 2);
            compute(0);
            asm volatile("s_waitcnt vmcnt(6)" ::: "memory");
            cw(RB, 1);
            asm volatile("s_waitcnt lgkmcnt(0)" ::: "memory");
            __builtin_amdgcn_s_barrier();
            load(RB, tt + 3);
            compute(1);
            asm volatile("s_waitcnt vmcnt(6)" ::: "memory");
            cw(RA, 0);
            asm volatile("s_waitcnt lgkmcnt(0)" ::: "memory");
            __builtin_amdgcn_s_barrier();
        }
        compute(0);                                      // tile 14
        asm volatile("s_waitcnt vmcnt(0)" ::: "memory");
        cw(RB, 1);                                       // tile 15
        asm volatile("s_waitcnt lgkmcnt(0)" ::: "memory");
        __builtin_amdgcn_s_barrier();
        compute(1);                                      // tile 15

        // V write (bf16): row = m0+wm+i*16+(lane>>4)*4+r, col = n0+j*16+l15
        const int crow = m0 + wm + (lane >> 4) * 4;
#pragma unroll
        for (int i = 0; i < 2; i++)
#pragma unroll
            for (int j = 0; j < 4; j++)
#pragma unroll
                for (int r = 0; r < 4; r++)
                    V[(size_t)(crow + i * 16 + r) * DM + n0 + j * 16 + l15] = f2bf(acc[i][j][r]);
        // csum: this wave's 32 rows = chunk (m0&2047)/32 + wave of (batch, head)
        float s[4];
#pragma unroll
        for (int j = 0; j < 4; j++) {
            s[j] = 0.f;
#pragma unroll
            for (int i = 0; i < 2; i++)
#pragma unroll
                for (int r = 0; r < 4; r++) s[j] += acc[i][j][r];
            s[j] += __shfl_xor(s[j], 16);
            s[j] += __shfl_xor(s[j], 32);
        }
        if (lane < 16) {
            int bi = (m0 >> 11) * NH + head;
            int chunk = ((m0 & (SEQ - 1)) >> 5) + wave;
#pragma unroll
            for (int j = 0; j < 4; j++)
                csum[(bi * NCHUNK + chunk) * 64 + j * 16 + lane] = s[j];
        }
    }
}

// z[q] = a*v[q] + w * sum_{p>q} v[p];  V bf16 in, Zb bf16 out [MROWS,512]
// Also converts Wo fp32 -> bf16 (one float4 per thread) so gemm can run
// unchanged; conversion is independent of the scan and overlaps it.
__global__ __launch_bounds__(256) void zbuild(
    const unsigned short* __restrict__ V, const float* __restrict__ csum,
    const float* __restrict__ cA, const float* __restrict__ cW,
    const float4* __restrict__ Wo, ushort4* __restrict__ wob,
    unsigned short* __restrict__ Zb) {
    // Wo conversion: 65536 float4 over 256 blocks x 256 threads
    {
        int idx = blockIdx.x * 256 + threadIdx.x;
        float4 v = Wo[idx];
        ushort4 o; o.x = f2bf(v.x); o.y = f2bf(v.y); o.z = f2bf(v.z); o.w = f2bf(v.w);
        wob[idx] = o;
    }
    int ci = blockIdx.x * 4 + (threadIdx.x >> 6);
    int h = threadIdx.x & 63;
    int c = ci & (NCHUNK - 1), bi = ci >> 6;
    int i = bi & 7, b = bi >> 3;
    float r = 0.f;
#pragma unroll 4
    for (int cc = c + 1; cc < NCHUNK; cc++) r += csum[((bi << 6) + cc) * 64 + h];
#pragma unroll 4
    for (int j = CHUNK - 1; j >= 0; j--) {
        int p = c * CHUNK + j;
        size_t row = (size_t)(b * SEQ + p);
        float v = bf2f(V[row * DM + i * DH + h]);
        float a = cA[row * NH + i], w = cW[row * NH + i];
        Zb[row * DM + i * DH + h] = f2bf(fmaf(a, v, w * r));
        r += v;
    }
}

// ---- C[M,N] = A[M,K] * B[N,K]^T (bf16 in, fp32 out), BK=32 4-buf -----------
template<int TM, int TN, int WM, int WN>
__global__ __launch_bounds__(256) void gemm_bt(
    const unsigned short* __restrict__ A, const unsigned short* __restrict__ B,
    float* __restrict__ C, int M, int N, int K)
{
    constexpr int ROWS = TM + TN;            // must be 128 (SPW=2, vmcnt imms)
    static_assert(ROWS == 128, "pipeline waits assume 128 staged rows");
    constexpr int MI = WM / 16, NJ = WN / 16;
    constexpr int WAVES_N = TN / WN;
    constexpr int TE = ROWS * 32;            // 4096 elems / buffer
    __shared__ __align__(16) unsigned short S[4 * TE];   // 32 KB
    const int t = threadIdx.x, lane = t & 63, wave = t >> 6;
    const int wm = (wave / WAVES_N) * WM, wn = (wave % WAVES_N) * WN;
    const int m0 = blockIdx.x * TM, n0 = blockIdx.y * TN;
    const int lr2 = lane >> 2;
    const int csrc = ((lane & 3) ^ ((lane >> 3) & 3)) * 8;
    const int l15 = lane & 15, q = lane >> 4;

    const unsigned short* gb[2];
#pragma unroll
    for (int r = 0; r < 2; r++) {
        int g = (r * 4 + wave) * 16 + lr2;
        gb[r] = (g < TM) ? A + (size_t)(m0 + g) * K + csrc
                         : B + (size_t)(n0 + g - TM) * K + csrc;
    }
    int aoff[MI], boff[NJ];
#pragma unroll
    for (int i = 0; i < MI; i++) {
        int R = wm + i * 16 + l15;
        aoff[i] = R * 32 + ((q ^ ((R >> 1) & 3)) * 8);
    }
#pragma unroll
    for (int j = 0; j < NJ; j++) {
        int R = TM + wn + j * 16 + l15;
        boff[j] = R * 32 + ((q ^ ((R >> 1) & 3)) * 8);
    }

    f32x4 acc[MI][NJ];
#pragma unroll
    for (int i = 0; i < MI; i++)
#pragma unroll
        for (int j = 0; j < NJ; j++) { f32x4 z = {0.f,0.f,0.f,0.f}; acc[i][j] = z; }

    auto stage = [&](int buf, int tt) {
        const int k0 = tt * 32;
#pragma unroll
        for (int r = 0; r < 2; r++)
            gl_lds16(gb[r] + k0, S + buf * TE + (r * 4 + wave) * 512);
    };
    auto compute = [&](int buf) {
        const unsigned short* Sb = S + buf * TE;
        bf16x8 af[MI], bfr[NJ];
#pragma unroll
        for (int i = 0; i < MI; i++) af[i] = *(const bf16x8*)(Sb + aoff[i]);
#pragma unroll
        for (int j = 0; j < NJ; j++) bfr[j] = *(const bf16x8*)(Sb + boff[j]);
        __builtin_amdgcn_s_setprio(1);
#pragma unroll
        for (int i = 0; i < MI; i++)
#pragma unroll
            for (int j = 0; j < NJ; j++)
                acc[i][j] = __builtin_amdgcn_mfma_f32_16x16x32_bf16(af[i], bfr[j], acc[i][j], 0, 0, 0);
        __builtin_amdgcn_s_setprio(0);
    };

    const int NT = K / 32;                   // 16 for K=512
    stage(0, 0); stage(1, 1); stage(2, 2);   // 6 loads in flight
    for (int tt = 0; tt < NT - 2; ++tt) {
        asm volatile("s_waitcnt vmcnt(4)" ::: "memory");
        __builtin_amdgcn_s_barrier();
        compute(tt & 3);
        if (tt + 3 < NT) stage((tt + 3) & 3, tt + 3);
    }
    asm volatile("s_waitcnt vmcnt(2)" ::: "memory");
    __builtin_amdgcn_s_barrier();
    compute((NT - 2) & 3);
    asm volatile("s_waitcnt vmcnt(0)" ::: "memory");
    __builtin_amdgcn_s_barrier();
    compute((NT - 1) & 3);

    const int crow = m0 + wm + (lane >> 4) * 4;
    const int ccol = n0 + wn + (lane & 15);
#pragma unroll
    for (int i = 0; i < MI; i++)
#pragma unroll
        for (int j = 0; j < NJ; j++)
#pragma unroll
            for (int r = 0; r < 4; r++)
                C[(size_t)(crow + i * 16 + r) * N + ccol + j * 16] = acc[i][j][r];
}

extern "C" void kernel_launch(void* const* d_in, const int* in_sizes, int n_in,
                              void* d_out, int out_size, void* d_ws, size_t ws_size,
                              hipStream_t stream) {
    const float* x  = (const float*)d_in[0];
    const float* Wq = (const float*)d_in[1];
    const float* Wk = (const float*)d_in[2];
    const float* Wv = (const float*)d_in[3];
    const float* Wo = (const float*)d_in[4];
    float* out = (float*)d_out;     // [2,2048,512] fp32
    char* ws = (char*)d_ws;         // ~15 MB used

    unsigned short* wb = (unsigned short*)(ws + 4194304);   // Wo bf16 @ +786432 elems
    unsigned short* V  = (unsigned short*)(ws + 6291456);   // 4 MB   [4096,512] bf16
    float* cA = (float*)(ws + 10485760);                    // 128 KB [4096,8]
    float* cW = (float*)(ws + 10616832);                    // 128 KB
    float* cs = (float*)(ws + 10747904);                    // 256 KB [16*64,64]
    unsigned short* Zb = (unsigned short*)(ws + 11010048);  // 4 MB   [4096,512] bf16

    proj<<<512, 256, 0, stream>>>(x, Wq, Wk, Wv, cA, cW, V, cs);
    zbuild<<<256, 256, 0, stream>>>(V, cs, cA, cW, (const float4*)Wo,
                                    (ushort4*)(wb + 786432), Zb);
    // out = Z @ Wo^T; 64x64 tile -> 512 blocks (2/CU)
    gemm_bt<64, 64, 32, 32><<<dim3(64, 8, 1), 256, 0, stream>>>(
        Zb, wb + 786432, out, MROWS, DM, DM);
}